// Round 8
// baseline (466.403 us; speedup 1.0000x reference)
//
#include <hip/hip_runtime.h>

#define T_STEPS 1024
#define CC 6
#define NCHUNK 32                  // time chunks per row (1 thread per chunk)
#define CHUNK (T_STEPS / NCHUNK)   // 32
#define WARM 8                     // warm-up steps (error ~0.08^7 * 5 ~ 1e-7)
#define KBUF 16                    // steps per register-buffered burst
#define NBLK (CHUNK / KBUF)        // 2 bursts per chunk
#define BUFN (KBUF * CC)           // 96 floats = 384 B = 3 x 128-B lines
#define LOG2E 1.4426950408889634f
#define LN2   0.6931471805599453f

__device__ __forceinline__ float fexp2(float x) {
#if __has_builtin(__builtin_amdgcn_exp2f)
    return __builtin_amdgcn_exp2f(x);
#else
    return exp2f(x);
#endif
}

__device__ __forceinline__ float flog2(float x) {
#if __has_builtin(__builtin_amdgcn_logf)
    return __builtin_amdgcn_logf(x);   // v_log_f32 = log2
#else
    return log2f(x);
#endif
}

// One THREAD per (row, time-chunk) chain: state (6) + row-softmax matrix (36)
// in registers; step = 36 mul + 36 exp2 + 30 add + 6 log2 + 12 fma, 36-wide
// ILP, no cross-lane dependency (rounds 3-5: cross-lane LDS round-trip in the
// serial chain was the killer; round 7 removed it).
//
// Round-8 fix: round 7's grid (NCHUNK=16) was a hard parallelism ceiling --
// 2048 waves = 8 waves/CU = 2/SIMD; VALUBusy 26% with everything stalled on
// unhidden vmem. NCHUNK=32 + WARM=8 doubles waves (16/CU, 4/SIMD) at the SAME
// total compute (warm fraction still 25%); warm re-reads are L3-absorbed
// (round-7 FETCH 136 MB < 201 MB input: input fits in 256-MB L3).
//
// IO: one 96-float register buffer per 16-step burst, loaded with 24 dwordx4,
// updated in place (step kk reads buf[kk*6..], overwrites with state; fully
// unrolled -> static indices), flushed with 24 dwordx4 = exactly 3 aligned
// 128-B lines per thread. Warm-up loads a half burst (8 steps, 12 dwordx4).
__global__ __launch_bounds__(256, 4) void transfer_kernel(
    const float* __restrict__ feats,
    const float* __restrict__ alpha,
    const float* __restrict__ trans,
    float* __restrict__ out, int B)
{
    int tid = blockIdx.x * blockDim.x + threadIdx.x;
    if (tid >= B * NCHUNK) return;
    int b = tid % B;   // consecutive threads -> consecutive rows
    int c = tid / B;   // wave-uniform chunk index (B % 64 == 0)

    // a = sigmoid(alpha)
    float a  = 1.0f / (1.0f + fexp2(-alpha[0] * LOG2E));
    float c1 = (1.0f - a) * LN2;   // (1-a)*ln2: log2-sum -> natural te

    // full row-softmax(trans), pre-scaled by log2e: tm[i][j] = Tn[i][j]*LOG2E
    float tm[CC][CC];
#pragma unroll
    for (int i = 0; i < CC; ++i) {
        float rs = 0.0f;
#pragma unroll
        for (int k = 0; k < CC; ++k)
            rs += fexp2(trans[i * CC + k] * LOG2E);
        float inv = LOG2E / rs;
#pragma unroll
        for (int jj = 0; jj < CC; ++jj)
            tm[i][jj] = fexp2(trans[i * CC + jj] * LOG2E) * inv;
    }

    const float* fb = feats + (size_t)b * T_STEPS * CC;
    float*       ob = out   + (size_t)b * T_STEPS * CC;

    float st[CC];
    float buf[BUFN];   // statically indexed everywhere after unroll

    // load N4 float4s (= N4*4 dwords) of x starting at step T0 into buf[0..)
#define LOADN(T0, N4)                                                        \
    do {                                                                     \
        _Pragma("unroll")                                                    \
        for (int k = 0; k < (N4); ++k) {                                     \
            float4 v = *reinterpret_cast<const float4*>(&fb[(T0) * CC + 4 * k]); \
            buf[4 * k + 0] = v.x; buf[4 * k + 1] = v.y;                      \
            buf[4 * k + 2] = v.z; buf[4 * k + 3] = v.w;                      \
        }                                                                    \
    } while (0)

    // advance one step using x = buf[KK*6..], write new state back in place
#define STEPB(KK)                                                         \
    do {                                                                  \
        float ns[CC];                                                     \
        _Pragma("unroll")                                                 \
        for (int jj = 0; jj < CC; ++jj) {                                 \
            float sum;                                                    \
            sum  = fexp2(st[0] * tm[0][jj]);                              \
            sum += fexp2(st[1] * tm[1][jj]);                              \
            sum += fexp2(st[2] * tm[2][jj]);                              \
            sum += fexp2(st[3] * tm[3][jj]);                              \
            sum += fexp2(st[4] * tm[4][jj]);                              \
            sum += fexp2(st[5] * tm[5][jj]);                              \
            ns[jj] = a * buf[(KK) * CC + jj] + c1 * flog2(sum);           \
        }                                                                 \
        _Pragma("unroll")                                                 \
        for (int jj = 0; jj < CC; ++jj) {                                 \
            st[jj] = ns[jj];                                              \
            buf[(KK) * CC + jj] = ns[jj];                                 \
        }                                                                 \
    } while (0)

    int t0 = c * CHUNK;

    if (c != 0) {
        // speculative warm-up: half-burst load at t0-WARM (>= 24, in-bounds;
        // byte base 24*(t0-8) is 16-B aligned), seed with x(tw), 7 steps
        LOADN(t0 - WARM, WARM * CC / 4);   // 12 float4 -> buf[0..47]
#pragma unroll
        for (int jj = 0; jj < CC; ++jj) st[jj] = buf[jj];
#pragma unroll
        for (int w = 1; w < WARM; ++w) STEPB(w);
    }
    // (c == 0: state initialized from t = 0 inside the first burst)

#pragma unroll 1
    for (int kb = 0; kb < NBLK; ++kb) {
        int tbase = t0 + kb * KBUF;
        LOADN(tbase, BUFN / 4);

        if (kb == 0 && c == 0) {        // wave-uniform branch
#pragma unroll
            for (int jj = 0; jj < CC; ++jj) st[jj] = buf[jj];  // t=0: emit as-is
#pragma unroll
            for (int kk = 1; kk < KBUF; ++kk) STEPB(kk);
        } else {
#pragma unroll
            for (int kk = 0; kk < KBUF; ++kk) STEPB(kk);
        }

        // flush: 24 dwordx4 = 96 dwords = 3 aligned 128-B lines
        // (byte base 24*tbase = 768c + 384kb -> 128-aligned)
#pragma unroll
        for (int k = 0; k < BUFN / 4; ++k) {
            float4 v = make_float4(buf[4 * k + 0], buf[4 * k + 1],
                                   buf[4 * k + 2], buf[4 * k + 3]);
            *reinterpret_cast<float4*>(&ob[tbase * CC + 4 * k]) = v;
        }
    }
#undef STEPB
#undef LOADN
}

extern "C" void kernel_launch(void* const* d_in, const int* in_sizes, int n_in,
                              void* d_out, int out_size, void* d_ws, size_t ws_size,
                              hipStream_t stream) {
    const float* feats = (const float*)d_in[0];
    const float* alpha = (const float*)d_in[1];
    const float* trans = (const float*)d_in[2];
    float* out = (float*)d_out;

    int B = in_sizes[0] / (T_STEPS * CC);   // 8192 (same convention as verified rounds)

    int threads = B * NCHUNK;               // 1 thread per (row, chunk)
    int block   = 256;
    int grid    = (threads + block - 1) / block;

    hipLaunchKernelGGL(transfer_kernel, dim3(grid), dim3(block), 0, stream,
                       feats, alpha, trans, out, B);
}